// Round 1
// baseline (43.151 us; speedup 1.0000x reference)
//
#include <hip/hip_runtime.h>

// PyramidROIAlign: B=2, N=1000, C=256, 7x7 pool, levels P2..P5 (256/128/64/32).
// One thread per float4 of output channels. Only the selected level is sampled.

__global__ __launch_bounds__(256) void roi_align_kernel(
    const float* __restrict__ boxes,   // [n_boxes,4] y1,x1,y2,x2
    const float* __restrict__ meta,    // [B,93], image shape at [4:7]
    const float* __restrict__ f2,      // [B,256,256,256]
    const float* __restrict__ f3,      // [B,128,128,256]
    const float* __restrict__ f4,      // [B, 64, 64,256]
    const float* __restrict__ f5,      // [B, 32, 32,256]
    float* __restrict__ out,           // [n_boxes,7,7,256]
    int boxes_per_batch,
    long total4)
{
    long idx = (long)blockIdx.x * blockDim.x + threadIdx.x;
    if (idx >= total4) return;

    int c4  = (int)(idx & 63);        // which float4 of the 256 channels
    long t  = idx >> 6;
    int p   = (int)(t % 49);          // pooled pixel 0..48
    int box = (int)(t / 49);
    int py = p / 7, px = p % 7;

    float by1 = boxes[4 * box + 0];
    float bx1 = boxes[4 * box + 1];
    float by2 = boxes[4 * box + 2];
    float bx2 = boxes[4 * box + 3];

    // level selection (matches jnp: clip(4 + round_half_even(log2(sqrt(hw)/ (224/sqrt(area)))), 2, 5))
    float h = by2 - by1, w = bx2 - bx1;
    float area  = meta[4] * meta[5];
    float scale = 224.0f / sqrtf(area);
    float rl    = log2f(sqrtf(h * w) / scale);
    int lvl = 4 + (int)rintf(rl);
    lvl = lvl < 2 ? 2 : (lvl > 5 ? 5 : lvl);
    int li = lvl - 2;
    const float* f = (li == 0) ? f2 : (li == 1) ? f3 : (li == 2) ? f4 : f5;
    int H = 256 >> li;                 // H == W per level

    int b = box / boxes_per_batch;

    // bilinear sample coordinates (exactly the reference arithmetic)
    float gy = (float)py / 6.0f;
    float gx = (float)px / 6.0f;
    float ys = (by1 + (by2 - by1) * gy) * (float)(H - 1);
    float xs = (bx1 + (bx2 - bx1) * gx) * (float)(H - 1);

    float fy0 = fminf(fmaxf(floorf(ys), 0.0f), (float)(H - 1));
    float fx0 = fminf(fmaxf(floorf(xs), 0.0f), (float)(H - 1));
    int y0 = (int)fy0, x0 = (int)fx0;
    int y1i = min(y0 + 1, H - 1);
    int x1i = min(x0 + 1, H - 1);
    float ly = ys - fy0;
    float lx = xs - fx0;

    const int C = 256;
    size_t row0 = ((size_t)b * H + y0)  * H;
    size_t row1 = ((size_t)b * H + y1i) * H;
    const float4* tl = (const float4*)(f + (row0 + x0)  * C) + c4;
    const float4* tr = (const float4*)(f + (row0 + x1i) * C) + c4;
    const float4* bl = (const float4*)(f + (row1 + x0)  * C) + c4;
    const float4* br = (const float4*)(f + (row1 + x1i) * C) + c4;

    float4 vtl = *tl, vtr = *tr, vbl = *bl, vbr = *br;
    float4 r;
    float top, bot;
    top = vtl.x + (vtr.x - vtl.x) * lx; bot = vbl.x + (vbr.x - vbl.x) * lx; r.x = top + (bot - top) * ly;
    top = vtl.y + (vtr.y - vtl.y) * lx; bot = vbl.y + (vbr.y - vbl.y) * lx; r.y = top + (bot - top) * ly;
    top = vtl.z + (vtr.z - vtl.z) * lx; bot = vbl.z + (vbr.z - vbl.z) * lx; r.z = top + (bot - top) * ly;
    top = vtl.w + (vtr.w - vtl.w) * lx; bot = vbl.w + (vbr.w - vbl.w) * lx; r.w = top + (bot - top) * ly;

    ((float4*)out)[idx] = r;
}

extern "C" void kernel_launch(void* const* d_in, const int* in_sizes, int n_in,
                              void* d_out, int out_size, void* d_ws, size_t ws_size,
                              hipStream_t stream) {
    const float* boxes = (const float*)d_in[0];
    const float* meta  = (const float*)d_in[1];
    const float* f2    = (const float*)d_in[2];
    const float* f3    = (const float*)d_in[3];
    const float* f4    = (const float*)d_in[4];
    const float* f5    = (const float*)d_in[5];
    float* out         = (float*)d_out;

    int n_boxes = in_sizes[0] / 4;                       // B*N = 2000
    int B       = in_sizes[2] / (256 * 256 * 256);       // feat_p2 elements / (H*W*C)
    int boxes_per_batch = n_boxes / B;                   // N = 1000

    long total4 = (long)n_boxes * 49 * 64;               // float4 outputs
    int blocks  = (int)((total4 + 255) / 256);
    roi_align_kernel<<<blocks, 256, 0, stream>>>(
        boxes, meta, f2, f3, f4, f5, out, boxes_per_batch, total4);
}

// Round 3
// 42.397 us; speedup vs baseline: 1.0178x; 1.0178x over previous
//
#include <hip/hip_runtime.h>
#include <math.h>

// PyramidROIAlign: B=2, N=1000, C=256, 7x7 pool, levels P2..P5 (256/128/64/32).
// Two-phase: prep kernel computes per-box level + per-axis sample info into ws;
// hot kernel is pure gather+lerp. Falls back to single-kernel if ws too small.

#define POOLN 7
#define CCH 256

typedef float f32x4 __attribute__((ext_vector_type(4)));

struct __align__(16) AxisInfo { int r0; int r1; float l; int pad; };

// ---------------- phase 1: per-(box, j) sampling info ----------------
__global__ __launch_bounds__(64) void roi_prep_kernel(
    const float* __restrict__ boxes,
    const float* __restrict__ meta,
    int* __restrict__ liArr,
    AxisInfo* __restrict__ yinfo,
    AxisInfo* __restrict__ xinfo,
    int n_boxes, int boxes_per_batch)
{
    int tid = blockIdx.x * blockDim.x + threadIdx.x;
    int box = tid / POOLN;
    int j   = tid - box * POOLN;
    if (box >= n_boxes) return;

    float by1 = boxes[4 * box + 0];
    float bx1 = boxes[4 * box + 1];
    float by2 = boxes[4 * box + 2];
    float bx2 = boxes[4 * box + 3];
    float h = by2 - by1, w = bx2 - bx1;

    // level selection: clip(4 + round_half_even(log2(sqrt(hw)/(224/sqrt(area)))), 2, 5)
    float area  = meta[4] * meta[5];
    float scale = 224.0f / sqrtf(area);
    float rl    = log2f(sqrtf(h * w) / scale);
    int lvl = 4 + (int)rintf(rl);
    lvl = lvl < 2 ? 2 : (lvl > 5 ? 5 : lvl);
    int li = lvl - 2;
    int H  = 256 >> li;                 // square levels
    if (j == 0) liArr[box] = li;

    int b = box / boxes_per_batch;
    float g = (float)j / 6.0f;          // arange(7)/(7-1), f32 division as in reference
    float hm1 = (float)(H - 1);

    // y axis (exact reference arithmetic order)
    float ys  = (by1 + h * g) * hm1;
    float fy0 = fminf(fmaxf(floorf(ys), 0.0f), hm1);
    int y0  = (int)fy0;
    int y1i = min(y0 + 1, H - 1);
    AxisInfo yi;
    yi.r0 = ((b * H + y0)  * H) * CCH;  // element offset of row start
    yi.r1 = ((b * H + y1i) * H) * CCH;
    yi.l  = ys - fy0;
    yi.pad = 0;
    yinfo[box * POOLN + j] = yi;

    // x axis
    float xs  = (bx1 + w * g) * hm1;
    float fx0 = fminf(fmaxf(floorf(xs), 0.0f), hm1);
    int x0  = (int)fx0;
    int x1i = min(x0 + 1, H - 1);
    AxisInfo xi;
    xi.r0 = x0  * CCH;
    xi.r1 = x1i * CCH;
    xi.l  = xs - fx0;
    xi.pad = 0;
    xinfo[box * POOLN + j] = xi;
}

// ---------------- phase 2: gather + bilinear lerp ----------------
__device__ __forceinline__ f32x4 bilerp4(f32x4 tl, f32x4 tr, f32x4 bl, f32x4 br,
                                         float lx, float ly)
{
    f32x4 r;
    float top, bot;
    top = tl.x + (tr.x - tl.x) * lx; bot = bl.x + (br.x - bl.x) * lx; r.x = top + (bot - top) * ly;
    top = tl.y + (tr.y - tl.y) * lx; bot = bl.y + (br.y - bl.y) * lx; r.y = top + (bot - top) * ly;
    top = tl.z + (tr.z - tl.z) * lx; bot = bl.z + (br.z - bl.z) * lx; r.z = top + (bot - top) * ly;
    top = tl.w + (tr.w - tl.w) * lx; bot = bl.w + (br.w - bl.w) * lx; r.w = top + (bot - top) * ly;
    return r;
}

__global__ __launch_bounds__(256) void roi_gather_kernel(
    const int* __restrict__ liArr,
    const AxisInfo* __restrict__ yinfo,
    const AxisInfo* __restrict__ xinfo,
    const float* __restrict__ f2,
    const float* __restrict__ f3,
    const float* __restrict__ f4,
    const float* __restrict__ f5,
    float* __restrict__ out,
    int q, int r, long total)
{
    // bijective XCD-chunked swizzle (nwg = 8q + r): same-XCD blocks get a
    // contiguous work range -> one box's reads stay in one L2.
    int bid    = blockIdx.x;
    int xcd    = bid & 7;
    int within = bid >> 3;
    int wg = (xcd < r ? xcd * (q + 1) : r * (q + 1) + (xcd - r) * q) + within;

    long wid = (long)wg * 256 + threadIdx.x;
    if (wid >= total) return;

    int  c4  = (int)(wid & 31);        // channel group: handles c4*4 and c4*4+128
    long t   = wid >> 5;               // global (box,pixel) index
    int  box = (int)(t / 49);
    int  p   = (int)(t - (long)box * 49);
    int  py  = (p * 37) >> 8;          // p/7 for p in [0,49)
    int  px  = p - py * 7;

    int li = liArr[box];
    const float* f = (li == 0) ? f2 : (li == 1) ? f3 : (li == 2) ? f4 : f5;
    AxisInfo yi = yinfo[box * POOLN + py];
    AxisInfo xi = xinfo[box * POOLN + px];
    float ly = yi.l, lx = xi.l;

    int co = c4 * 4;
    const float* ptl = f + yi.r0 + xi.r0 + co;
    const float* ptr2= f + yi.r0 + xi.r1 + co;
    const float* pbl = f + yi.r1 + xi.r0 + co;
    const float* pbr = f + yi.r1 + xi.r1 + co;

    f32x4 tlA = *(const f32x4*)ptl;
    f32x4 trA = *(const f32x4*)ptr2;
    f32x4 blA = *(const f32x4*)pbl;
    f32x4 brA = *(const f32x4*)pbr;
    f32x4 tlB = *(const f32x4*)(ptl + 128);
    f32x4 trB = *(const f32x4*)(ptr2 + 128);
    f32x4 blB = *(const f32x4*)(pbl + 128);
    f32x4 brB = *(const f32x4*)(pbr + 128);

    f32x4 rA = bilerp4(tlA, trA, blA, brA, lx, ly);
    f32x4 rB = bilerp4(tlB, trB, blB, brB, lx, ly);

    long obase = t * CCH + co;
    __builtin_nontemporal_store(rA, (f32x4*)(out + obase));
    __builtin_nontemporal_store(rB, (f32x4*)(out + obase + 128));
}

// ---------------- fallback: round-1 single kernel ----------------
__global__ __launch_bounds__(256) void roi_align_kernel(
    const float* __restrict__ boxes,
    const float* __restrict__ meta,
    const float* __restrict__ f2,
    const float* __restrict__ f3,
    const float* __restrict__ f4,
    const float* __restrict__ f5,
    float* __restrict__ out,
    int boxes_per_batch,
    long total4)
{
    long idx = (long)blockIdx.x * blockDim.x + threadIdx.x;
    if (idx >= total4) return;

    int c4  = (int)(idx & 63);
    long t  = idx >> 6;
    int p   = (int)(t % 49);
    int box = (int)(t / 49);
    int py = p / 7, px = p % 7;

    float by1 = boxes[4 * box + 0];
    float bx1 = boxes[4 * box + 1];
    float by2 = boxes[4 * box + 2];
    float bx2 = boxes[4 * box + 3];

    float h = by2 - by1, w = bx2 - bx1;
    float area  = meta[4] * meta[5];
    float scale = 224.0f / sqrtf(area);
    float rl    = log2f(sqrtf(h * w) / scale);
    int lvl = 4 + (int)rintf(rl);
    lvl = lvl < 2 ? 2 : (lvl > 5 ? 5 : lvl);
    int li = lvl - 2;
    const float* f = (li == 0) ? f2 : (li == 1) ? f3 : (li == 2) ? f4 : f5;
    int H = 256 >> li;

    int b = box / boxes_per_batch;

    float gy = (float)py / 6.0f;
    float gx = (float)px / 6.0f;
    float ys = (by1 + (by2 - by1) * gy) * (float)(H - 1);
    float xs = (bx1 + (bx2 - bx1) * gx) * (float)(H - 1);

    float fy0 = fminf(fmaxf(floorf(ys), 0.0f), (float)(H - 1));
    float fx0 = fminf(fmaxf(floorf(xs), 0.0f), (float)(H - 1));
    int y0 = (int)fy0, x0 = (int)fx0;
    int y1i = min(y0 + 1, H - 1);
    int x1i = min(x0 + 1, H - 1);
    float ly = ys - fy0;
    float lx = xs - fx0;

    size_t row0 = ((size_t)b * H + y0)  * H;
    size_t row1 = ((size_t)b * H + y1i) * H;
    const f32x4* tl = (const f32x4*)(f + (row0 + x0)  * CCH) + c4;
    const f32x4* tr = (const f32x4*)(f + (row0 + x1i) * CCH) + c4;
    const f32x4* bl = (const f32x4*)(f + (row1 + x0)  * CCH) + c4;
    const f32x4* br = (const f32x4*)(f + (row1 + x1i) * CCH) + c4;

    f32x4 rr = bilerp4(*tl, *tr, *bl, *br, lx, ly);
    ((f32x4*)out)[idx] = rr;
}

extern "C" void kernel_launch(void* const* d_in, const int* in_sizes, int n_in,
                              void* d_out, int out_size, void* d_ws, size_t ws_size,
                              hipStream_t stream) {
    const float* boxes = (const float*)d_in[0];
    const float* meta  = (const float*)d_in[1];
    const float* f2    = (const float*)d_in[2];
    const float* f3    = (const float*)d_in[3];
    const float* f4    = (const float*)d_in[4];
    const float* f5    = (const float*)d_in[5];
    float* out         = (float*)d_out;

    int n_boxes = in_sizes[0] / 4;                       // B*N = 2000
    int B       = in_sizes[2] / (256 * 256 * 256);       // batch from feat_p2
    int boxes_per_batch = n_boxes / B;                   // N

    size_t li_bytes   = 16384;                           // int[n_boxes], padded
    size_t axis_bytes = (size_t)n_boxes * POOLN * sizeof(AxisInfo);
    size_t need = li_bytes + 2 * axis_bytes;

    if (d_ws != nullptr && ws_size >= need) {
        int*      liArr = (int*)d_ws;
        AxisInfo* yinfo = (AxisInfo*)((char*)d_ws + li_bytes);
        AxisInfo* xinfo = yinfo + (size_t)n_boxes * POOLN;

        int prep_threads = n_boxes * POOLN;
        roi_prep_kernel<<<(prep_threads + 63) / 64, 64, 0, stream>>>(
            boxes, meta, liArr, yinfo, xinfo, n_boxes, boxes_per_batch);

        long total = (long)n_boxes * 49 * 32;            // threads (8 ch each)
        int  nwg   = (int)((total + 255) / 256);
        int  q = nwg >> 3, r = nwg & 7;
        roi_gather_kernel<<<nwg, 256, 0, stream>>>(
            liArr, yinfo, xinfo, f2, f3, f4, f5, out, q, r, total);
    } else {
        long total4 = (long)n_boxes * 49 * 64;
        int  blocks = (int)((total4 + 255) / 256);
        roi_align_kernel<<<blocks, 256, 0, stream>>>(
            boxes, meta, f2, f3, f4, f5, out, boxes_per_batch, total4);
    }
}